// Round 1
// baseline (62.054 us; speedup 1.0000x reference)
//
#include <hip/hip_runtime.h>

// Problem constants (from reference):
// values: (B=2, T=3, N=6, H=256, W=704, C=17) float32
// indices: (P=500000, 3) int32 ; coors: (P, 2) float32
// out: (P, 17) float32  — bilinear sample with out-of-bounds corners zeroed.
#define B_ 2
#define T_ 3
#define N_ 6
#define H_ 256
#define W_ 704
#define C_ 17
#define P_ 500000

// One point per 32-lane group; lane index = channel (17 active / 32).
// Corner reads are 17 contiguous floats -> coalesced 68B segments per group.
__global__ __launch_bounds__(256) void bilerp_gather_kernel(
    const float* __restrict__ values,
    const int*   __restrict__ indices,
    const float* __restrict__ coors,
    float*       __restrict__ out)
{
    int gid = blockIdx.x * blockDim.x + threadIdx.x;
    int p = gid >> 5;        // point index
    int c = gid & 31;        // channel lane
    if (p >= P_ || c >= C_) return;

    int ib = indices[p * 3 + 0];
    int it = indices[p * 3 + 1];
    int in = indices[p * 3 + 2];
    int flat = (ib * T_ + it) * N_ + in;   // < 36

    float iy = coors[p * 2 + 0] - 0.5f;
    float ix = coors[p * 2 + 1] - 0.5f;
    float x0f = floorf(ix);
    float y0f = floorf(iy);
    float wx = ix - x0f;
    float wy = iy - y0f;
    int x0 = (int)x0f;
    int y0 = (int)y0f;
    int x1 = x0 + 1;
    int y1 = y0 + 1;

    // Image base: flat * H*W*C ; max total index ~110M fits int32.
    const float* __restrict__ img = values + (size_t)flat * (H_ * W_ * C_);

    bool xin0 = (x0 >= 0) & (x0 < W_);
    bool xin1 = (x1 >= 0) & (x1 < W_);
    bool yin0 = (y0 >= 0) & (y0 < H_);
    bool yin1 = (y1 >= 0) & (y1 < H_);

    float v00 = 0.f, v01 = 0.f, v10 = 0.f, v11 = 0.f;
    if (yin0) {
        const float* row = img + (size_t)y0 * (W_ * C_);
        if (xin0) v00 = row[x0 * C_ + c];
        if (xin1) v01 = row[x1 * C_ + c];
    }
    if (yin1) {
        const float* row = img + (size_t)y1 * (W_ * C_);
        if (xin0) v10 = row[x0 * C_ + c];
        if (xin1) v11 = row[x1 * C_ + c];
    }

    float w00 = (1.f - wx) * (1.f - wy);
    float w01 = wx * (1.f - wy);
    float w10 = (1.f - wx) * wy;
    float w11 = wx * wy;

    out[p * C_ + c] = v00 * w00 + v01 * w01 + v10 * w10 + v11 * w11;
}

extern "C" void kernel_launch(void* const* d_in, const int* in_sizes, int n_in,
                              void* d_out, int out_size, void* d_ws, size_t ws_size,
                              hipStream_t stream)
{
    const float* values  = (const float*)d_in[0];
    const int*   indices = (const int*)d_in[1];
    const float* coors   = (const float*)d_in[2];
    float* out = (float*)d_out;

    const int threads_per_point = 32;
    const long long total_threads = (long long)P_ * threads_per_point;
    const int block = 256;
    const int grid = (int)((total_threads + block - 1) / block);

    bilerp_gather_kernel<<<grid, block, 0, stream>>>(values, indices, coors, out);
}

// Round 2
// 50.695 us; speedup vs baseline: 1.2241x; 1.2241x over previous
//
#include <hip/hip_runtime.h>

// Problem constants (from reference):
// values: (B=2, T=3, N=6, H=256, W=704, C=17) float32
// indices: (P=500000, 3) int32 ; coors: (P, 2) float32
// out: (P, 17) float32  — bilinear sample with out-of-bounds corners zeroed.
#define B_ 2
#define T_ 3
#define N_ 6
#define H_ 256
#define W_ 704
#define C_ 17
#define P_ 500000

// 3 points per wave64 (51/64 lanes active; lane -> (sub-point, channel)).
// All 4 corner loads issued unconditionally from clamped addresses; OOB
// corners handled by zeroing the weight (cndmask), not by branching.
__global__ __launch_bounds__(256) void bilerp_gather_kernel(
    const float* __restrict__ values,
    const int*   __restrict__ indices,
    const float* __restrict__ coors,
    float*       __restrict__ out)
{
    const int tid  = threadIdx.x;
    const int wave = blockIdx.x * (blockDim.x >> 6) + (tid >> 6);
    const int lane = tid & 63;
    const int sub  = lane / 17;            // 0..2 active, 3 = idle tail lanes
    const int c    = lane - sub * 17;      // channel 0..16
    const int p    = wave * 3 + sub;       // point index
    if (sub >= 3 || p >= P_) return;

    const int ib = indices[p * 3 + 0];
    const int it = indices[p * 3 + 1];
    const int in = indices[p * 3 + 2];
    const int flat = (ib * T_ + it) * N_ + in;   // < 36

    const float iy = coors[p * 2 + 0] - 0.5f;
    const float ix = coors[p * 2 + 1] - 0.5f;
    const float x0f = floorf(ix);
    const float y0f = floorf(iy);
    const float wx = ix - x0f;
    const float wy = iy - y0f;
    const int x0 = (int)x0f;
    const int y0 = (int)y0f;
    const int x1 = x0 + 1;
    const int y1 = y0 + 1;

    // Clamped coordinates for unconditional loads.
    const int x0c = min(max(x0, 0), W_ - 1);
    const int x1c = min(max(x1, 0), W_ - 1);
    const int y0c = min(max(y0, 0), H_ - 1);
    const int y1c = min(max(y1, 0), H_ - 1);

    const float* __restrict__ img = values + (size_t)flat * (H_ * W_ * C_);

    // Issue all 4 gathers back-to-back (max MLP, no divergence).
    const float v00 = img[((size_t)y0c * W_ + x0c) * C_ + c];
    const float v01 = img[((size_t)y0c * W_ + x1c) * C_ + c];
    const float v10 = img[((size_t)y1c * W_ + x0c) * C_ + c];
    const float v11 = img[((size_t)y1c * W_ + x1c) * C_ + c];

    const bool xin0 = (x0 >= 0) & (x0 < W_);
    const bool xin1 = (x1 >= 0) & (x1 < W_);
    const bool yin0 = (y0 >= 0) & (y0 < H_);
    const bool yin1 = (y1 >= 0) & (y1 < H_);

    float w00 = (1.f - wx) * (1.f - wy);
    float w01 = wx * (1.f - wy);
    float w10 = (1.f - wx) * wy;
    float w11 = wx * wy;
    w00 = (xin0 & yin0) ? w00 : 0.f;
    w01 = (xin1 & yin0) ? w01 : 0.f;
    w10 = (xin0 & yin1) ? w10 : 0.f;
    w11 = (xin1 & yin1) ? w11 : 0.f;

    const float r = v00 * w00 + v01 * w01 + v10 * w10 + v11 * w11;
    __builtin_nontemporal_store(r, &out[(size_t)p * C_ + c]);
}

extern "C" void kernel_launch(void* const* d_in, const int* in_sizes, int n_in,
                              void* d_out, int out_size, void* d_ws, size_t ws_size,
                              hipStream_t stream)
{
    const float* values  = (const float*)d_in[0];
    const int*   indices = (const int*)d_in[1];
    const float* coors   = (const float*)d_in[2];
    float* out = (float*)d_out;

    // 3 points per wave64, 4 waves per 256-thread block -> 12 points/block.
    const int block = 256;
    const int points_per_block = 12;
    const int grid = (P_ + points_per_block - 1) / points_per_block;

    bilerp_gather_kernel<<<grid, block, 0, stream>>>(values, indices, coors, out);
}